// Round 1
// 124.670 us; speedup vs baseline: 1.2418x; 1.2418x over previous
//
#include <hip/hip_runtime.h>

#define NB 2
#define NG 1024
#define HEIGHT 128
#define WIDTH 128
#define HW (HEIGHT * WIDTH)
#define NSEG 16
#define SEGLEN (NG / NSEG)                 // 64
#define ITEM_STRIDE (8 + SEGLEN * 20 + 8)  // header + items + trailing run = 1296 floats
#define E10 4.5399931e-05f                 // exp(-10)

// ws layout (floats)
#define REC_U 0                            // unsorted records: 2048*16
#define REC_S 32768                        // sorted records:   2048*16
#define Z_U   65536                        // unsorted z:       2048
#define ITEMS 67584                        // 32 streams * ITEM_STRIDE = 41472
#define RGBOF 109056                       // rendered rgb:     6*HW = 98304
#define P_ENT 207360                       // 8 entropy partials
#define P_L1D 207368                       // 512 depth-l1 partials
#define P_SSS 207880                       // 384 ssim partials
#define P_SSL 208264                       // 384 rgb-l1 partials
// record: [0]px [1]py [2]hx [3]hy [4]i00 [5]i01 [6]i11 [7]op [8]c0 [9]c1 [10]c2 [11]z [12]e10op [13..15]pad
// item:   [0]runT [1..3]runRGB [4]runD [5]px [6]py [7]hx [8]hy [9]i00 [10]i01 [11]i11 [12]op [13]c0 [14]c1 [15]c2 [16]z

__device__ inline float blk_reduce(float v, float* sh) {
    for (int off = 32; off > 0; off >>= 1) v += __shfl_down(v, off, 64);
    int lane = threadIdx.x & 63;
    int w = threadIdx.x >> 6;
    __syncthreads();
    if (lane == 0) sh[w] = v;
    __syncthreads();
    float s = 0.f;
    if (threadIdx.x == 0) {
        int nw = (blockDim.x + 63) >> 6;
        for (int i = 0; i < nw; i++) s += sh[i];
    }
    return s;  // valid on thread 0 only
}

// ---------------- per-gaussian preprocess (8 blocks x 256) ----------------
__global__ __launch_bounds__(256) void k_pre(const float* __restrict__ g,
                                             const float* __restrict__ intr,
                                             float* __restrict__ ws) {
    __shared__ float sh[8];
    int idx = blockIdx.x * 256 + threadIdx.x;  // 0..2047
    int b = idx >> 10;
    const float* row = g + (size_t)idx * 38;
    float mx = row[0], my = row[1], mz = row[2];
    float sx = row[3], sy = row[4], sz = row[5];
    float qw = row[6], qx = row[7], qy = row[8], qz = row[9];
    float op = row[10];
    float sh0 = row[11], sh1 = row[12], sh2 = row[13];
    float fx = intr[b * 9 + 0], fy = intr[b * 9 + 4];
    float cx = intr[b * 9 + 2], cy = intr[b * 9 + 5];

    float z = fmaxf(mz, 1e-4f);
    float px = fx * mx / z + cx;
    float py = fy * my / z + cy;

    float r00 = 1.f - 2.f * (qy * qy + qz * qz), r01 = 2.f * (qx * qy - qw * qz), r02 = 2.f * (qx * qz + qw * qy);
    float r10 = 2.f * (qx * qy + qw * qz), r11 = 1.f - 2.f * (qx * qx + qz * qz), r12 = 2.f * (qy * qz - qw * qx);
    float r20 = 2.f * (qx * qz - qw * qy), r21 = 2.f * (qy * qz + qw * qx), r22 = 1.f - 2.f * (qx * qx + qy * qy);
    float a00 = r00 * sx, a01 = r01 * sy, a02 = r02 * sz;
    float a10 = r10 * sx, a11 = r11 * sy, a12 = r12 * sz;
    float a20 = r20 * sx, a21 = r21 * sy, a22 = r22 * sz;
    float m00 = a00 * a00 + a01 * a01 + a02 * a02;
    float m01 = a00 * a10 + a01 * a11 + a02 * a12;
    float m02 = a00 * a20 + a01 * a21 + a02 * a22;
    float m11 = a10 * a10 + a11 * a11 + a12 * a12;
    float m12 = a10 * a20 + a11 * a21 + a12 * a22;
    float m22 = a20 * a20 + a21 * a21 + a22 * a22;

    float zc = fmaxf(mz, 1e-6f);
    float aJ = fx / zc, bJ = -fx * mx / (zc * zc);
    float cJ = fy / zc, dJ = -fy * my / (zc * zc);
    float c00 = aJ * aJ * m00 + 2.f * aJ * bJ * m02 + bJ * bJ * m22 + 0.3f;
    float c01 = cJ * (aJ * m01 + bJ * m12) + dJ * (aJ * m02 + bJ * m22);
    float c11 = cJ * cJ * m11 + 2.f * cJ * dJ * m12 + dJ * dJ * m22 + 0.3f;
    float det = fmaxf(c00 * c11 - c01 * c01, 1e-8f);
    float i00 = c11 / det;
    float i11 = c00 / det;
    float i01 = -c01 / det;

    const float C0c = 0.28209479177387814f;
    float col0 = fminf(fmaxf(sh0 * C0c + 0.5f, 0.f), 1.f);
    float col1 = fminf(fmaxf(sh1 * C0c + 0.5f, 0.f), 1.f);
    float col2 = fminf(fmaxf(sh2 * C0c + 0.5f, 0.f), 1.f);

    float hx = sqrtf(20.f * c00);  // power>-10 ellipse bbox half-extents
    float hy = sqrtf(20.f * c11);

    float* rec = ws + REC_U + (size_t)idx * 16;
    rec[0] = px; rec[1] = py; rec[2] = hx; rec[3] = hy;
    rec[4] = i00; rec[5] = i01; rec[6] = i11; rec[7] = op;
    rec[8] = col0; rec[9] = col1; rec[10] = col2; rec[11] = z;
    rec[12] = E10 * op; rec[13] = 0.f; rec[14] = 0.f; rec[15] = 0.f;
    ws[Z_U + idx] = z;

    float o = fminf(fmaxf(op, 1e-6f), 1.f - 1e-6f);
    float ent = -(o * logf(o) + (1.f - o) * logf(1.f - o));
    float s = blk_reduce(ent, sh);
    if (threadIdx.x == 0) ws[P_ENT + blockIdx.x] = s;
}

// ---------------- rank sort + record scatter (32 blocks x 256) ----------------
// Block = (batch, group-of-64 gaussians). z staged in LDS; 4 threads split the
// j-scan per gaussian (64 iters each), partial ranks combined in LDS.
__global__ __launch_bounds__(256) void k_rank(float* __restrict__ ws) {
    __shared__ float zs[NG];
    __shared__ int sp[256];
    int bid = blockIdx.x;        // 0..31
    int b = bid >> 4;            // batch
    int grp = bid & 15;          // which 64 gaussians
    int tid = threadIdx.x;
    const float* zb = ws + Z_U + (b << 10);
    ((float4*)zs)[tid] = ((const float4*)zb)[tid];  // stage 1024 z (4KB)
    __syncthreads();
    int il = (grp << 6) + (tid & 63);  // local gaussian 0..1023
    int jq = tid >> 6;                 // j-quarter 0..3 (wave-uniform)
    float zi = zs[il];
    int rank = 0;
    int j0 = jq << 8;
#pragma unroll 4
    for (int j = j0; j < j0 + 256; j += 4) {
        float4 zq = *(const float4*)(zs + j);  // uniform addr -> LDS broadcast
        rank += (zq.x < zi) || (zq.x == zi && (j + 0) < il);
        rank += (zq.y < zi) || (zq.y == zi && (j + 1) < il);
        rank += (zq.z < zi) || (zq.z == zi && (j + 2) < il);
        rank += (zq.w < zi) || (zq.w == zi && (j + 3) < il);
    }
    sp[tid] = rank;
    __syncthreads();
    if (tid < 64) {
        int r = sp[tid] + sp[tid + 64] + sp[tid + 128] + sp[tid + 192];
        int gi = (b << 10) + il;
        const float4* src = (const float4*)(ws + REC_U + (size_t)gi * 16);
        float4 r0 = src[0], r1 = src[1], r2 = src[2], r3 = src[3];
        float4* dst = (float4*)(ws + REC_S + (size_t)((b << 10) + r) * 16);
        dst[0] = r0; dst[1] = r1; dst[2] = r2; dst[3] = r3;
    }
}

// ---------------- build compacted item streams (32 blocks x 64) ----------------
// One wave per stream: barrier-free segmented affine scan via shuffles.
// inactive j: (T,c) -> (T*(1-a_j), c + T*a_j*col_j)  with a_j = exp(-10)*op_j
// active   j: identity + segment flag (scan resets after it).
__global__ __launch_bounds__(64) void k_items(float* __restrict__ ws) {
    int s = blockIdx.x;  // 0..31 = (batch, seg)
    int b = s >> 4, seg = s & 15;
    int k = threadIdx.x;  // 0..63
    const float* r = ws + REC_S + (size_t)((b << 10) + (seg << 6) + k) * 16;
    float4 q0 = ((const float4*)r)[0];  // px py hx hy
    float4 q1 = ((const float4*)r)[1];  // i00 i01 i11 op
    float4 q2 = ((const float4*)r)[2];  // c0 c1 c2 z
    float a10 = r[12];                  // exp(-10)*op
    bool act = (q0.x + q0.z >= 0.f) && (q0.x - q0.z <= 127.f) &&
               (q0.y + q0.w >= 0.f) && (q0.y - q0.w <= 127.f);
    float T, cr, cg, cb, cd;
    int f, cnt;
    if (act) {
        T = 1.f; cr = 0.f; cg = 0.f; cb = 0.f; cd = 0.f; f = 1; cnt = 1;
    } else {
        T = 1.f - a10;
        cr = a10 * q2.x; cg = a10 * q2.y; cb = a10 * q2.z; cd = a10 * q2.w;
        f = 0; cnt = 0;
    }
#pragma unroll
    for (int off = 1; off < 64; off <<= 1) {
        float pT = __shfl_up(T, off, 64);
        float pr = __shfl_up(cr, off, 64);
        float pg = __shfl_up(cg, off, 64);
        float pb = __shfl_up(cb, off, 64);
        float pd = __shfl_up(cd, off, 64);
        int pf = __shfl_up(f, off, 64);
        int pc = __shfl_up(cnt, off, 64);
        if (k >= off) {
            cnt += pc;
            if (!f) {  // absorb left partial unless a segment starts inside ours
                cr = pr + pT * cr;
                cg = pg + pT * cg;
                cb = pb + pT * cb;
                cd = pd + pT * cd;
                T = pT * T;
                f = pf;
            }
        }
    }
    // exclusive (run-before-me) values
    float eT = __shfl_up(T, 1, 64);
    float er = __shfl_up(cr, 1, 64);
    float eg = __shfl_up(cg, 1, 64);
    float eb = __shfl_up(cb, 1, 64);
    float ed = __shfl_up(cd, 1, 64);
    if (k == 0) { eT = 1.f; er = 0.f; eg = 0.f; eb = 0.f; ed = 0.f; }
    float* out = ws + ITEMS + (size_t)s * ITEM_STRIDE;
    if (act) {
        float* itp = out + 8 + (size_t)(cnt - 1) * 20;
        ((float4*)itp)[0] = make_float4(eT, er, eg, eb);
        ((float4*)itp)[1] = make_float4(ed, q0.x, q0.y, q0.z);
        ((float4*)itp)[2] = make_float4(q0.w, q1.x, q1.y, q1.z);
        ((float4*)itp)[3] = make_float4(q1.w, q2.x, q2.y, q2.z);
        itp[16] = q2.w;
    }
    if (k == 63) {  // trailing run (identity if 63 is active) + header
        float* itp = out + 8 + (size_t)cnt * 20;
        itp[0] = T; itp[1] = cr; itp[2] = cg; itp[3] = cb; itp[4] = cd;
        ((int*)out)[0] = cnt;
    }
}

// ---------------- render: one 8x8 tile per block, 16 z-segment waves ----------------
__global__ __launch_bounds__(1024, 8) void k_render(const float* __restrict__ tgt_d,
                                                    float* __restrict__ ws) {
    __shared__ float comb[5][1024];
    int tid = threadIdx.x;
    int lane = tid & 63;
    int seg = tid >> 6;    // 0..15
    int blk = blockIdx.x;  // 512 tiles
    int b = blk >> 8;
    int t = blk & 255;
    int x0 = (t & 15) * 8, y0 = (t >> 4) * 8;
    int x = x0 + (lane & 7), y = y0 + (lane >> 3);

    const float* base = ws + ITEMS + (size_t)(b * NSEG + seg) * ITEM_STRIDE;
    int n = ((const int*)base)[0];
    const float* it = base + 8;

    float xf = (float)x, yf = (float)y;
    float x0f = (float)x0, x1f = (float)(x0 + 7);
    float y0f = (float)y0, y1f = (float)(y0 + 7);
    float T = 1.f, cr = 0.f, cg = 0.f, cb = 0.f, cd = 0.f;
    for (int i = 0; i < n; i++, it += 20) {
        float4 A = ((const float4*)it)[0];   // runT runR runG runB
        float4 Bv = ((const float4*)it)[1];  // runD px py hx
        float4 C = ((const float4*)it)[2];   // hy i00 i01 i11
        float4 D = ((const float4*)it)[3];   // op c0 c1 c2
        float z = it[16];
        // preceding inactive-run composite
        cr += T * A.y; cg += T * A.z; cb += T * A.w; cd += T * Bv.x;
        T *= A.x;
        // the active gaussian
        float px = Bv.y, py = Bv.z, hx = Bv.w, hy = C.x;
        float op = D.x;
        float a;
        if (px + hx >= x0f && px - hx <= x1f && py + hy >= y0f && py - hy <= y1f) {
            float dx = xf - px, dy = yf - py;
            float q = C.y * dx * dx + 2.f * C.z * dx * dy + C.w * dy * dy;
            float pw = fminf(fmaxf(-0.5f * q, -10.f), 0.f);
            a = fminf(__expf(pw) * op, 0.99f);
        } else {
            a = E10 * op;  // clamped outside its ellipse: pixel-independent (exact)
        }
        float w = T * a;
        cr += w * D.y; cg += w * D.z; cb += w * D.w; cd += w * z;
        T -= w;  // T *= (1-a)
    }
    // trailing run
    {
        float4 A = ((const float4*)it)[0];
        float rd = it[4];
        cr += T * A.y; cg += T * A.z; cb += T * A.w; cd += T * rd;
        T *= A.x;
    }

    comb[0][tid] = T;
    comb[1][tid] = cr;
    comb[2][tid] = cg;
    comb[3][tid] = cb;
    comb[4][tid] = cd;
    __syncthreads();

    if (tid < 64) {
        float T0 = comb[0][tid], r0 = comb[1][tid], g0 = comb[2][tid];
        float b0 = comb[3][tid], d0 = comb[4][tid];
#pragma unroll
        for (int sgi = 1; sgi < NSEG; sgi++) {
            int j = sgi * 64 + tid;
            r0 += T0 * comb[1][j];
            g0 += T0 * comb[2][j];
            b0 += T0 * comb[3][j];
            d0 += T0 * comb[4][j];
            T0 *= comb[0][j];
        }
        r0 = fminf(fmaxf(r0, 0.f), 1.f);
        g0 = fminf(fmaxf(g0, 0.f), 1.f);
        b0 = fminf(fmaxf(b0, 0.f), 1.f);
        float* rgb = ws + RGBOF;
        rgb[((b * 3 + 0) * HEIGHT + y) * WIDTH + x] = r0;
        rgb[((b * 3 + 1) * HEIGHT + y) * WIDTH + x] = g0;
        rgb[((b * 3 + 2) * HEIGHT + y) * WIDTH + x] = b0;
        float l1d = fabsf(d0 - tgt_d[(b * HEIGHT + y) * WIDTH + x]);
        for (int off = 32; off > 0; off >>= 1) l1d += __shfl_down(l1d, off, 64);
        if (tid == 0) ws[P_L1D + blk] = l1d;
    }
}

// ---------------- SSIM + rgb L1 (384 blocks x 256) ----------------
__global__ __launch_bounds__(256) void k_ssim(const float* __restrict__ tgt_rgb,
                                              float* __restrict__ ws) {
    __shared__ float sh[8];
    int idx = blockIdx.x * 256 + threadIdx.x;  // < 98304
    const float* img1 = ws + RGBOF;
    int bc = idx >> 14;
    int pix = idx & (HW - 1);
    int y = pix >> 7, x = pix & 127;

    float gg[7];
    float gs = 0.f;
#pragma unroll
    for (int i = 0; i < 7; i++) {
        float c = (float)(i - 3);
        gg[i] = __expf(-c * c / 4.5f);
        gs += gg[i];
    }
#pragma unroll
    for (int i = 0; i < 7; i++) gg[i] /= gs;

    float mu1 = 0.f, mu2 = 0.f, s11 = 0.f, s22 = 0.f, s12 = 0.f;
    int plane = bc * HW;
#pragma unroll
    for (int dy = -3; dy <= 3; dy++) {
        int yy = y + dy;
#pragma unroll
        for (int dx = -3; dx <= 3; dx++) {
            int xx = x + dx;
            float w = gg[dy + 3] * gg[dx + 3];
            float i1 = 0.f, i2 = 0.f;
            if (yy >= 0 && yy < HEIGHT && xx >= 0 && xx < WIDTH) {
                int o = plane + yy * WIDTH + xx;
                i1 = img1[o];
                i2 = tgt_rgb[o];
            }
            mu1 += w * i1;
            mu2 += w * i2;
            s11 += w * i1 * i1;
            s22 += w * i2 * i2;
            s12 += w * i1 * i2;
        }
    }
    float v1 = s11 - mu1 * mu1;
    float v2 = s22 - mu2 * mu2;
    float cv = s12 - mu1 * mu2;
    const float C1 = 1e-4f, C2 = 9e-4f;
    float ssim = ((2.f * mu1 * mu2 + C1) * (2.f * cv + C2)) /
                 ((mu1 * mu1 + mu2 * mu2 + C1) * (v1 + v2 + C2));
    float l1 = fabsf(img1[idx] - tgt_rgb[idx]);

    float s_ssim = blk_reduce(ssim, sh);
    float s_l1 = blk_reduce(l1, sh);
    if (threadIdx.x == 0) {
        ws[P_SSS + blockIdx.x] = s_ssim;
        ws[P_SSL + blockIdx.x] = s_l1;
    }
}

// ---------------- final reduce (1 block x 256) ----------------
__global__ __launch_bounds__(256) void k_final(const float* __restrict__ ws_c,
                                               float* __restrict__ out) {
    __shared__ float sh[8];
    float e = 0.f, d = 0.f, ss = 0.f, sl = 0.f;
    for (int i = threadIdx.x; i < 512; i += 256) d += ws_c[P_L1D + i];
    for (int i = threadIdx.x; i < 384; i += 256) { ss += ws_c[P_SSS + i]; sl += ws_c[P_SSL + i]; }
    if (threadIdx.x < 8) e = ws_c[P_ENT + threadIdx.x];
    float rd_ = blk_reduce(d, sh);
    float rss = blk_reduce(ss, sh);
    float rsl = blk_reduce(sl, sh);
    float re = blk_reduce(e, sh);
    if (threadIdx.x == 0) {
        float l1r = rsl / (float)(NB * 3 * HW);
        float ssim = rss / (float)(NB * 3 * HW);
        float l1d = rd_ / (float)(NB * HW);
        float opa = re / (float)(NB * NG);
        out[0] = 0.8f * l1r + 0.2f * (1.f - ssim) + 0.5f * l1d + 0.01f * opa;
    }
}

extern "C" void kernel_launch(void* const* d_in, const int* in_sizes, int n_in,
                              void* d_out, int out_size, void* d_ws, size_t ws_size,
                              hipStream_t stream) {
    const float* g = (const float*)d_in[0];
    const float* intr = (const float*)d_in[1];
    const float* trgb = (const float*)d_in[2];
    const float* tdep = (const float*)d_in[3];
    float* ws = (float*)d_ws;
    float* out = (float*)d_out;

    hipLaunchKernelGGL(k_pre, dim3(8), dim3(256), 0, stream, g, intr, ws);
    hipLaunchKernelGGL(k_rank, dim3(32), dim3(256), 0, stream, ws);
    hipLaunchKernelGGL(k_items, dim3(NB * NSEG), dim3(64), 0, stream, ws);
    hipLaunchKernelGGL(k_render, dim3(NB * 256), dim3(1024), 0, stream, tdep, ws);
    hipLaunchKernelGGL(k_ssim, dim3((NB * 3 * HW) / 256), dim3(256), 0, stream, trgb, ws);
    hipLaunchKernelGGL(k_final, dim3(1), dim3(256), 0, stream, ws, out);
}

// Round 2
// 97.653 us; speedup vs baseline: 1.5854x; 1.2767x over previous
//
#include <hip/hip_runtime.h>

#define NB 2
#define NG 1024
#define HEIGHT 128
#define WIDTH 128
#define HW (HEIGHT * WIDTH)
#define E10 4.5399931e-05f                 // exp(-10)

// ws layout (floats)
#define REC_U 0                            // unsorted records: 2048*16
#define REC_S 32768                        // sorted records:   2048*16
#define Z_U   65536                        // unsorted z:       2048
#define PFX   67584                        // background prefix: 2 * 1025 * 8 = 16400
#define TCNT  83984                        // 512 tile counts (int)
#define TLIST 84496                        // 512 tiles * 1024 u16 = 262144 float-slots
#define RGBOF 346640                       // rendered rgb: 6*HW = 98304
#define P_ENT 444944                       // 8 entropy partials
#define P_L1D 444952                       // 512 depth-l1 partials
#define P_SSS 445464                       // 384 ssim partials
#define P_SSL 445848                       // 384 rgb-l1 partials
// record: [0]px [1]py [2]hx [3]hy [4]i00 [5]i01 [6]i11 [7]op [8]c0 [9]c1 [10]c2 [11]z [12]e10op [13..15]pad
// prefix P_k (stride 8): [0]Tt [1]Ur [2]Ug [3]Ub [4]Ud  (background affine of ranks [0,k))

__device__ inline float blk_reduce(float v, float* sh) {
    for (int off = 32; off > 0; off >>= 1) v += __shfl_down(v, off, 64);
    int lane = threadIdx.x & 63;
    int w = threadIdx.x >> 6;
    __syncthreads();
    if (lane == 0) sh[w] = v;
    __syncthreads();
    float s = 0.f;
    if (threadIdx.x == 0) {
        int nw = (blockDim.x + 63) >> 6;
        for (int i = 0; i < nw; i++) s += sh[i];
    }
    return s;  // valid on thread 0 only
}

// ---------------- per-gaussian preprocess (8 blocks x 256) ----------------
__global__ __launch_bounds__(256) void k_pre(const float* __restrict__ g,
                                             const float* __restrict__ intr,
                                             float* __restrict__ ws) {
    __shared__ float sh[8];
    int idx = blockIdx.x * 256 + threadIdx.x;  // 0..2047
    int b = idx >> 10;
    const float* row = g + (size_t)idx * 38;
    float mx = row[0], my = row[1], mz = row[2];
    float sx = row[3], sy = row[4], sz = row[5];
    float qw = row[6], qx = row[7], qy = row[8], qz = row[9];
    float op = row[10];
    float sh0 = row[11], sh1 = row[12], sh2 = row[13];
    float fx = intr[b * 9 + 0], fy = intr[b * 9 + 4];
    float cx = intr[b * 9 + 2], cy = intr[b * 9 + 5];

    float z = fmaxf(mz, 1e-4f);
    float px = fx * mx / z + cx;
    float py = fy * my / z + cy;

    float r00 = 1.f - 2.f * (qy * qy + qz * qz), r01 = 2.f * (qx * qy - qw * qz), r02 = 2.f * (qx * qz + qw * qy);
    float r10 = 2.f * (qx * qy + qw * qz), r11 = 1.f - 2.f * (qx * qx + qz * qz), r12 = 2.f * (qy * qz - qw * qx);
    float r20 = 2.f * (qx * qz - qw * qy), r21 = 2.f * (qy * qz + qw * qx), r22 = 1.f - 2.f * (qx * qx + qy * qy);
    float a00 = r00 * sx, a01 = r01 * sy, a02 = r02 * sz;
    float a10 = r10 * sx, a11 = r11 * sy, a12 = r12 * sz;
    float a20 = r20 * sx, a21 = r21 * sy, a22 = r22 * sz;
    float m00 = a00 * a00 + a01 * a01 + a02 * a02;
    float m01 = a00 * a10 + a01 * a11 + a02 * a12;
    float m02 = a00 * a20 + a01 * a21 + a02 * a22;
    float m11 = a10 * a10 + a11 * a11 + a12 * a12;
    float m12 = a10 * a20 + a11 * a21 + a12 * a22;
    float m22 = a20 * a20 + a21 * a21 + a22 * a22;

    float zc = fmaxf(mz, 1e-6f);
    float aJ = fx / zc, bJ = -fx * mx / (zc * zc);
    float cJ = fy / zc, dJ = -fy * my / (zc * zc);
    float c00 = aJ * aJ * m00 + 2.f * aJ * bJ * m02 + bJ * bJ * m22 + 0.3f;
    float c01 = cJ * (aJ * m01 + bJ * m12) + dJ * (aJ * m02 + bJ * m22);
    float c11 = cJ * cJ * m11 + 2.f * cJ * dJ * m12 + dJ * dJ * m22 + 0.3f;
    float det = fmaxf(c00 * c11 - c01 * c01, 1e-8f);
    float i00 = c11 / det;
    float i11 = c00 / det;
    float i01 = -c01 / det;

    const float C0c = 0.28209479177387814f;
    float col0 = fminf(fmaxf(sh0 * C0c + 0.5f, 0.f), 1.f);
    float col1 = fminf(fmaxf(sh1 * C0c + 0.5f, 0.f), 1.f);
    float col2 = fminf(fmaxf(sh2 * C0c + 0.5f, 0.f), 1.f);

    float hx = sqrtf(20.f * c00);  // power>-10 ellipse bbox half-extents
    float hy = sqrtf(20.f * c11);

    float* rec = ws + REC_U + (size_t)idx * 16;
    rec[0] = px; rec[1] = py; rec[2] = hx; rec[3] = hy;
    rec[4] = i00; rec[5] = i01; rec[6] = i11; rec[7] = op;
    rec[8] = col0; rec[9] = col1; rec[10] = col2; rec[11] = z;
    rec[12] = E10 * op; rec[13] = 0.f; rec[14] = 0.f; rec[15] = 0.f;
    ws[Z_U + idx] = z;

    float o = fminf(fmaxf(op, 1e-6f), 1.f - 1e-6f);
    float ent = -(o * logf(o) + (1.f - o) * logf(1.f - o));
    float s = blk_reduce(ent, sh);
    if (threadIdx.x == 0) ws[P_ENT + blockIdx.x] = s;
}

// ---------------- rank sort + record scatter (32 blocks x 256) ----------------
__global__ __launch_bounds__(256) void k_rank(float* __restrict__ ws) {
    __shared__ float zs[NG];
    __shared__ int sp[256];
    int bid = blockIdx.x;        // 0..31
    int b = bid >> 4;            // batch
    int grp = bid & 15;          // which 64 gaussians
    int tid = threadIdx.x;
    const float* zb = ws + Z_U + (b << 10);
    ((float4*)zs)[tid] = ((const float4*)zb)[tid];  // stage 1024 z (4KB)
    __syncthreads();
    int il = (grp << 6) + (tid & 63);  // local gaussian
    int jq = tid >> 6;                 // j-quarter 0..3 (wave-uniform)
    float zi = zs[il];
    int rank = 0;
    int j0 = jq << 8;
#pragma unroll 4
    for (int j = j0; j < j0 + 256; j += 4) {
        float4 zq = *(const float4*)(zs + j);
        rank += (zq.x < zi) || (zq.x == zi && (j + 0) < il);
        rank += (zq.y < zi) || (zq.y == zi && (j + 1) < il);
        rank += (zq.z < zi) || (zq.z == zi && (j + 2) < il);
        rank += (zq.w < zi) || (zq.w == zi && (j + 3) < il);
    }
    sp[tid] = rank;
    __syncthreads();
    if (tid < 64) {
        int r = sp[tid] + sp[tid + 64] + sp[tid + 128] + sp[tid + 192];
        int gi = (b << 10) + il;
        const float4* src = (const float4*)(ws + REC_U + (size_t)gi * 16);
        float4 r0 = src[0], r1 = src[1], r2 = src[2], r3 = src[3];
        float4* dst = (float4*)(ws + REC_S + (size_t)((b << 10) + r) * 16);
        dst[0] = r0; dst[1] = r1; dst[2] = r2; dst[3] = r3;
    }
}

// ---------------- background prefix scan (2 blocks x 1024) ----------------
// P_k = background affine of z-ranks [0,k): (T,C) -> (T*Tt_k, C + T*U_k)
__global__ __launch_bounds__(1024) void k_scan(float* __restrict__ ws) {
    __shared__ float st[NG], sur[NG], sug[NG], sub_[NG], sud[NG];
    int b = blockIdx.x;
    int k = threadIdx.x;
    const float* r = ws + REC_S + (size_t)((b << 10) + k) * 16;
    float4 f1 = ((const float4*)r)[1];  // i00 i01 i11 op
    float4 f2 = ((const float4*)r)[2];  // c0 c1 c2 z
    float a10 = E10 * f1.w;
    st[k] = 1.f - a10;
    sur[k] = a10 * f2.x; sug[k] = a10 * f2.y; sub_[k] = a10 * f2.z; sud[k] = a10 * f2.w;
    __syncthreads();
    for (int off = 1; off < NG; off <<= 1) {
        float tl = 1.f, url = 0.f, ugl = 0.f, ubl = 0.f, udl = 0.f;
        if (k >= off) {
            tl = st[k - off]; url = sur[k - off]; ugl = sug[k - off];
            ubl = sub_[k - off]; udl = sud[k - off];
        }
        __syncthreads();
        if (k >= off) {
            sur[k] = url + tl * sur[k];
            sug[k] = ugl + tl * sug[k];
            sub_[k] = ubl + tl * sub_[k];
            sud[k] = udl + tl * sud[k];
            st[k] = tl * st[k];
        }
        __syncthreads();
    }
    float* P = ws + PFX + (size_t)b * 8200;
    ((float4*)(P + (size_t)(k + 1) * 8))[0] = make_float4(st[k], sur[k], sug[k], sub_[k]);
    P[(size_t)(k + 1) * 8 + 4] = sud[k];
    if (k == 0) {
        ((float4*)P)[0] = make_float4(1.f, 0.f, 0.f, 0.f);
        P[4] = 0.f;
    }
}

// ---------------- per-tile binning (512 blocks x 256) ----------------
// Tile = 8x8. Emit z-ordered list of overlapping gaussian ranks (u16).
__global__ __launch_bounds__(256) void k_bin(float* __restrict__ ws) {
    __shared__ int sc[256];
    int blk = blockIdx.x;  // 0..511
    int b = blk >> 8;
    int t = blk & 255;
    float x0f = (float)((t & 15) * 8), x1f = x0f + 7.f;
    float y0f = (float)((t >> 4) * 8), y1f = y0f + 7.f;
    int tid = threadIdx.x;
    int r0 = tid * 4;
    int pred = 0;
#pragma unroll
    for (int j = 0; j < 4; j++) {
        float4 bb = ((const float4*)(ws + REC_S + (size_t)((b << 10) + r0 + j) * 16))[0];
        bool ov = (bb.x + bb.z >= x0f) && (bb.x - bb.z <= x1f) &&
                  (bb.y + bb.w >= y0f) && (bb.y - bb.w <= y1f);
        pred |= (int)ov << j;
    }
    int cnt = __popc(pred);
    sc[tid] = cnt;
    __syncthreads();
    for (int off = 1; off < 256; off <<= 1) {
        int v = 0;
        if (tid >= off) v = sc[tid - off];
        __syncthreads();
        sc[tid] += v;
        __syncthreads();
    }
    unsigned short* list = (unsigned short*)(ws + TLIST) + (size_t)blk * 1024;
    int pos = sc[tid] - cnt;  // exclusive offset, z-order preserved
#pragma unroll
    for (int j = 0; j < 4; j++)
        if (pred & (1 << j)) list[pos++] = (unsigned short)(r0 + j);
    if (tid == 255) ((int*)(ws + TCNT))[blk] = sc[255];
}

// ---------------- render: tile list + background prefix (512 blocks x 1024) ----
// 16 waves split the tile's item list into contiguous z-chunks; background
// runs between listed items come from the prefix array P (group-quotient).
// tau-invariant: physical T = tau * Tt_pe / Tt_s0  (one reciprocal per wave).
__global__ __launch_bounds__(1024, 8) void k_render(const float* __restrict__ tgt_d,
                                                    float* __restrict__ ws) {
    __shared__ float comb[5][1024];
    int tid = threadIdx.x;
    int lane = tid & 63;
    int wv = tid >> 6;     // 0..15 z-chunk
    int blk = blockIdx.x;  // 512 tiles
    int b = blk >> 8;
    int t = blk & 255;
    int x0 = (t & 15) * 8, y0 = (t >> 4) * 8;
    int x = x0 + (lane & 7), y = y0 + (lane >> 3);
    float xf = (float)x, yf = (float)y;

    int cnt = ((const int*)(ws + TCNT))[blk];
    const unsigned short* list = (const unsigned short*)(ws + TLIST) + (size_t)blk * 1024;
    const float* P = ws + PFX + (size_t)b * 8200;
    const float* recs = ws + REC_S + (size_t)(b << 10) * 16;

    int m = (cnt + 15) >> 4;
    int p0 = wv * m; if (p0 > cnt) p0 = cnt;
    int p1 = p0 + m; if (p1 > cnt) p1 = cnt;
    int s0 = (p0 == 0) ? 0 : (int)list[p0 - 1] + 1;

    float4 Pa = *(const float4*)(P + (size_t)s0 * 8);
    float Pud = P[(size_t)s0 * 8 + 4];
    float inv0 = 1.f / Pa.x;  // 1 / Tt_s0  (in [1, 1.05])
    float Pur = Pa.y, Pug = Pa.z, Pub = Pa.w;

    float tau = 1.f, cr = 0.f, cg = 0.f, cb = 0.f, cd = 0.f;
    for (int p = p0; p < p1; p++) {
        int r = (int)list[p];
        float4 Qa = *(const float4*)(P + (size_t)r * 8);
        float Qud = P[(size_t)r * 8 + 4];
        const float* rec = recs + (size_t)r * 16;
        float4 g0 = ((const float4*)rec)[0];  // px py hx hy
        float4 g1 = ((const float4*)rec)[1];  // i00 i01 i11 op
        float4 g2 = ((const float4*)rec)[2];  // c0 c1 c2 z
        float kap = tau * inv0;
        // background run [pe, r)
        cr += kap * (Qa.y - Pur);
        cg += kap * (Qa.z - Pug);
        cb += kap * (Qa.w - Pub);
        cd += kap * (Qud - Pud);
        // item r (exact: clamp covers out-of-ellipse pixels)
        float dx = xf - g0.x, dy = yf - g0.y;
        float q = g1.x * dx * dx + 2.f * g1.y * dx * dy + g1.z * dy * dy;
        float pw = fminf(fmaxf(-0.5f * q, -10.f), 0.f);
        float a = fminf(__expf(pw) * g1.w, 0.99f);
        float w = kap * Qa.x * a;
        cr += w * g2.x; cg += w * g2.y; cb += w * g2.z; cd += w * g2.w;
        float a10 = E10 * g1.w;
        tau *= (1.f - a) * (1.f + a10 * (1.f + a10));  // /(1-a10) to 2nd order
        // advance prefix boundary to r+1 in-register
        float s = Qa.x * a10;
        Pur = Qa.y + s * g2.x;
        Pug = Qa.z + s * g2.y;
        Pub = Qa.w + s * g2.z;
        Pud = Qud + s * g2.w;
    }
    // trailing background run to chunk end (wave 15 extends to NG)
    int e0 = (wv == 15) ? NG : ((p1 == 0) ? 0 : (int)list[p1 - 1] + 1);
    float4 Ea = *(const float4*)(P + (size_t)e0 * 8);
    float Eud = P[(size_t)e0 * 8 + 4];
    float kapf = tau * inv0;
    cr += kapf * (Ea.y - Pur);
    cg += kapf * (Ea.z - Pug);
    cb += kapf * (Ea.w - Pub);
    cd += kapf * (Eud - Pud);
    float T = tau * Ea.x * inv0;

    comb[0][tid] = T;
    comb[1][tid] = cr;
    comb[2][tid] = cg;
    comb[3][tid] = cb;
    comb[4][tid] = cd;
    __syncthreads();

    if (tid < 64) {
        float T0 = comb[0][tid], r0 = comb[1][tid], g0 = comb[2][tid];
        float b0 = comb[3][tid], d0 = comb[4][tid];
#pragma unroll
        for (int sgi = 1; sgi < 16; sgi++) {
            int j = sgi * 64 + tid;
            r0 += T0 * comb[1][j];
            g0 += T0 * comb[2][j];
            b0 += T0 * comb[3][j];
            d0 += T0 * comb[4][j];
            T0 *= comb[0][j];
        }
        r0 = fminf(fmaxf(r0, 0.f), 1.f);
        g0 = fminf(fmaxf(g0, 0.f), 1.f);
        b0 = fminf(fmaxf(b0, 0.f), 1.f);
        float* rgb = ws + RGBOF;
        rgb[((b * 3 + 0) * HEIGHT + y) * WIDTH + x] = r0;
        rgb[((b * 3 + 1) * HEIGHT + y) * WIDTH + x] = g0;
        rgb[((b * 3 + 2) * HEIGHT + y) * WIDTH + x] = b0;
        float l1d = fabsf(d0 - tgt_d[(b * HEIGHT + y) * WIDTH + x]);
        for (int off = 32; off > 0; off >>= 1) l1d += __shfl_down(l1d, off, 64);
        if (tid == 0) ws[P_L1D + blk] = l1d;
    }
}

// ---------------- SSIM + rgb L1 (384 blocks x 256) ----------------
__global__ __launch_bounds__(256) void k_ssim(const float* __restrict__ tgt_rgb,
                                              float* __restrict__ ws) {
    __shared__ float sh[8];
    int idx = blockIdx.x * 256 + threadIdx.x;  // < 98304
    const float* img1 = ws + RGBOF;
    int bc = idx >> 14;
    int pix = idx & (HW - 1);
    int y = pix >> 7, x = pix & 127;

    float gg[7];
    float gs = 0.f;
#pragma unroll
    for (int i = 0; i < 7; i++) {
        float c = (float)(i - 3);
        gg[i] = __expf(-c * c / 4.5f);
        gs += gg[i];
    }
#pragma unroll
    for (int i = 0; i < 7; i++) gg[i] /= gs;

    float mu1 = 0.f, mu2 = 0.f, s11 = 0.f, s22 = 0.f, s12 = 0.f;
    int plane = bc * HW;
#pragma unroll
    for (int dy = -3; dy <= 3; dy++) {
        int yy = y + dy;
#pragma unroll
        for (int dx = -3; dx <= 3; dx++) {
            int xx = x + dx;
            float w = gg[dy + 3] * gg[dx + 3];
            float i1 = 0.f, i2 = 0.f;
            if (yy >= 0 && yy < HEIGHT && xx >= 0 && xx < WIDTH) {
                int o = plane + yy * WIDTH + xx;
                i1 = img1[o];
                i2 = tgt_rgb[o];
            }
            mu1 += w * i1;
            mu2 += w * i2;
            s11 += w * i1 * i1;
            s22 += w * i2 * i2;
            s12 += w * i1 * i2;
        }
    }
    float v1 = s11 - mu1 * mu1;
    float v2 = s22 - mu2 * mu2;
    float cv = s12 - mu1 * mu2;
    const float C1 = 1e-4f, C2 = 9e-4f;
    float ssim = ((2.f * mu1 * mu2 + C1) * (2.f * cv + C2)) /
                 ((mu1 * mu1 + mu2 * mu2 + C1) * (v1 + v2 + C2));
    float l1 = fabsf(img1[idx] - tgt_rgb[idx]);

    float s_ssim = blk_reduce(ssim, sh);
    float s_l1 = blk_reduce(l1, sh);
    if (threadIdx.x == 0) {
        ws[P_SSS + blockIdx.x] = s_ssim;
        ws[P_SSL + blockIdx.x] = s_l1;
    }
}

// ---------------- final reduce (1 block x 256) ----------------
__global__ __launch_bounds__(256) void k_final(const float* __restrict__ ws_c,
                                               float* __restrict__ out) {
    __shared__ float sh[8];
    float e = 0.f, d = 0.f, ss = 0.f, sl = 0.f;
    for (int i = threadIdx.x; i < 512; i += 256) d += ws_c[P_L1D + i];
    for (int i = threadIdx.x; i < 384; i += 256) { ss += ws_c[P_SSS + i]; sl += ws_c[P_SSL + i]; }
    if (threadIdx.x < 8) e = ws_c[P_ENT + threadIdx.x];
    float rd_ = blk_reduce(d, sh);
    float rss = blk_reduce(ss, sh);
    float rsl = blk_reduce(sl, sh);
    float re = blk_reduce(e, sh);
    if (threadIdx.x == 0) {
        float l1r = rsl / (float)(NB * 3 * HW);
        float ssim = rss / (float)(NB * 3 * HW);
        float l1d = rd_ / (float)(NB * HW);
        float opa = re / (float)(NB * NG);
        out[0] = 0.8f * l1r + 0.2f * (1.f - ssim) + 0.5f * l1d + 0.01f * opa;
    }
}

extern "C" void kernel_launch(void* const* d_in, const int* in_sizes, int n_in,
                              void* d_out, int out_size, void* d_ws, size_t ws_size,
                              hipStream_t stream) {
    const float* g = (const float*)d_in[0];
    const float* intr = (const float*)d_in[1];
    const float* trgb = (const float*)d_in[2];
    const float* tdep = (const float*)d_in[3];
    float* ws = (float*)d_ws;
    float* out = (float*)d_out;

    hipLaunchKernelGGL(k_pre, dim3(8), dim3(256), 0, stream, g, intr, ws);
    hipLaunchKernelGGL(k_rank, dim3(32), dim3(256), 0, stream, ws);
    hipLaunchKernelGGL(k_scan, dim3(NB), dim3(1024), 0, stream, ws);
    hipLaunchKernelGGL(k_bin, dim3(NB * 256), dim3(256), 0, stream, ws);
    hipLaunchKernelGGL(k_render, dim3(NB * 256), dim3(1024), 0, stream, tdep, ws);
    hipLaunchKernelGGL(k_ssim, dim3((NB * 3 * HW) / 256), dim3(256), 0, stream, trgb, ws);
    hipLaunchKernelGGL(k_final, dim3(1), dim3(256), 0, stream, ws, out);
}